// Round 2
// baseline (265.490 us; speedup 1.0000x reference)
//
#include <hip/hip_runtime.h>
#include <stdint.h>

#define S_LEN 512
#define I_DIM 28
#define H_DIM 128
#define O_DIM 28
#define BT    8    // batch rows per block (rows 8..15 of MFMA are dup/garbage)

typedef __attribute__((ext_vector_type(8))) short bf16x8;
typedef __attribute__((ext_vector_type(4))) float f32x4;

__device__ __forceinline__ short f2bf(float f) {        // cold paths only
    unsigned u = __float_as_uint(f);
    u = (u + 0x7fffu + ((u >> 16) & 1u)) >> 16;
    return (short)u;
}
__device__ __forceinline__ float bf2f(unsigned short u) {
    return __uint_as_float(((unsigned)u) << 16);
}
__device__ __forceinline__ unsigned cvt_pk(float a, float b) {
    unsigned r;
    asm("v_cvt_pk_bf16_f32 %0, %1, %2" : "=v"(r) : "v"(a), "v"(b));
    return r;
}
// tanh(a) = 1 - 2/(1+e^{2a}) : 3 VALU + 2 trans (no fp-div sequence)
#define TWO_LOG2E 2.8853900817779268f
__device__ __forceinline__ float fast_tanh(float a) {
    float e = __builtin_amdgcn_exp2f(a * TWO_LOG2E);
    float r = __builtin_amdgcn_rcpf(1.0f + e);
    return fmaf(-2.0f, r, 1.0f);
}

__global__ __launch_bounds__(512, 4) void rnn_fused(
    const float* __restrict__ x,
    const float* __restrict__ W_ih, const float* __restrict__ b_ih,
    const float* __restrict__ W_hh, const float* __restrict__ b_hh,
    const float* __restrict__ W_ho, const float* __restrict__ b_ho,
    float* __restrict__ out)
{
    const int tid  = threadIdx.x;
    const int wave = tid >> 6;         // 0..7 -> h-column tile j0 = wave*16
    const int lane = tid & 63;
    const int l15  = lane & 15;
    const int l7   = lane & 7;
    const int lk   = lane >> 4;        // 0..3 (k-group within MFMA fragment)
    const int r0   = blockIdx.x * BT;  // batch-row base

    __shared__ __align__(16) unsigned short hbuf[2][BT * H_DIM]; // 4KB, XOR-swizzled
    __shared__ bf16x8 xstage[16][32];                            // compact x ring, 8KB

    // ---- constant B fragments (registers, all 512 steps) ----
    const int jcol = wave * 16 + l15;
    bf16x8 bw[4];
    #pragma unroll
    for (int kk = 0; kk < 4; ++kk)
        #pragma unroll
        for (int e = 0; e < 8; ++e)
            bw[kk][e] = f2bf(W_hh[(kk * 32 + lk * 8 + e) * H_DIM + jcol]);
    bf16x8 bx;
    #pragma unroll
    for (int e = 0; e < 8; ++e) {
        int k = lk * 8 + e;
        bx[e] = (k < I_DIM) ? f2bf(W_ih[k * H_DIM + jcol]) : (short)0;
    }
    const float bias = b_ih[jcol] + b_hh[jcol];

    // ---- per-lane LDS byte offsets ----
    int ha_off[4];                      // A-frag reads: row = l15&7 (dup), 16B
    #pragma unroll
    for (int kk = 0; kk < 4; ++kk)
        ha_off[kk] = ((l7 * 256) + (kk * 64) + (lk * 16)) ^ (l7 << 4);
    int hw_off[4];                      // writes: row = lk*4+r (only lk<2 valid)
    #pragma unroll
    for (int r = 0; r < 4; ++r) {
        int row = (lk * 4 + r) & 7;
        hw_off[r] = (row * 256 + jcol * 2) ^ (row << 4);
    }

    for (int i = tid; i < BT * H_DIM; i += 512) hbuf[0][i] = 0;  // h0 = 0

    const bool ldx  = (l15 < 8);        // this lane loads a real x row
    const bool hasHi = (lk < 3);        // k-group 3: only k=24..27 valid
    const float* xbase = x + (size_t)(r0 + l7) * S_LEN * I_DIM + lk * 8;

    // ---- stage x frames 0..7 (wave w stages frame w) ----
    {
        float4 lo = make_float4(0.f,0.f,0.f,0.f), hi = lo;
        if (ldx) {
            const float* src = xbase + wave * I_DIM;
            lo = *(const float4*)src;
            if (hasHi) hi = *(const float4*)(src + 4);
        }
        if (ldx) {
            union { bf16x8 v; unsigned u[4]; } f;
            f.u[0] = cvt_pk(lo.x, lo.y); f.u[1] = cvt_pk(lo.z, lo.w);
            f.u[2] = cvt_pk(hi.x, hi.y); f.u[3] = cvt_pk(hi.z, hi.w);
            xstage[wave][lk * 8 + l7] = f.v;
        }
    }
    asm volatile("s_waitcnt lgkmcnt(0)" ::: "memory");
    __builtin_amdgcn_s_barrier();
    asm volatile("" ::: "memory");

    // ---- time loop: 8 steps per outer iteration ----
    for (int t8 = 0; t8 < S_LEN; t8 += 8) {
        const int tf = t8 + 8 + wave;                    // frame this wave prefetches
        float4 pf_lo = make_float4(0.f,0.f,0.f,0.f), pf_hi = pf_lo;
        if (tf < S_LEN && ldx) {
            const float* src = xbase + (size_t)tf * I_DIM;
            pf_lo = *(const float4*)src;
            if (hasHi) pf_hi = *(const float4*)(src + 4);
        }
        bf16x8 axf[8];
        #pragma unroll
        for (int p = 0; p < 8; ++p)
            axf[p] = xstage[(t8 + p) & 15][lk * 8 + l7];

        #pragma unroll
        for (int p = 0; p < 8; ++p) {
            const char* rb = (const char*)hbuf[p & 1];
            char*       wb = (char*)hbuf[(p & 1) ^ 1];

            // dual accumulator chains (depth 3 + depth 2)
            f32x4 acc0 = {bias, bias, bias, bias};
            f32x4 acc1 = {0.f, 0.f, 0.f, 0.f};
            acc0 = __builtin_amdgcn_mfma_f32_16x16x32_bf16(axf[p], bx, acc0, 0, 0, 0);
            bf16x8 ah0 = *(const bf16x8*)(rb + ha_off[0]);
            acc1 = __builtin_amdgcn_mfma_f32_16x16x32_bf16(ah0, bw[0], acc1, 0, 0, 0);
            bf16x8 ah1 = *(const bf16x8*)(rb + ha_off[1]);
            acc0 = __builtin_amdgcn_mfma_f32_16x16x32_bf16(ah1, bw[1], acc0, 0, 0, 0);
            bf16x8 ah2 = *(const bf16x8*)(rb + ha_off[2]);
            acc1 = __builtin_amdgcn_mfma_f32_16x16x32_bf16(ah2, bw[2], acc1, 0, 0, 0);
            bf16x8 ah3 = *(const bf16x8*)(rb + ha_off[3]);
            acc0 = __builtin_amdgcn_mfma_f32_16x16x32_bf16(ah3, bw[3], acc0, 0, 0, 0);

            if (lk < 2) {                                // rows 0..7 only
                #pragma unroll
                for (int r = 0; r < 4; ++r) {
                    float hv = fast_tanh(acc0[r] + acc1[r]);
                    *(unsigned short*)(wb + hw_off[r]) = (unsigned short)cvt_pk(hv, hv);
                }
            }
            if (p == 6 && tf < S_LEN && ldx) {           // late LDS write of prefetch
                union { bf16x8 v; unsigned u[4]; } f;
                f.u[0] = cvt_pk(pf_lo.x, pf_lo.y); f.u[1] = cvt_pk(pf_lo.z, pf_lo.w);
                f.u[2] = cvt_pk(pf_hi.x, pf_hi.y); f.u[3] = cvt_pk(pf_hi.z, pf_hi.w);
                xstage[tf & 15][lk * 8 + l7] = f.v;
            }
            asm volatile("s_waitcnt lgkmcnt(0)" ::: "memory");
            __builtin_amdgcn_s_barrier();
            asm volatile("" ::: "memory");
        }
    }

    // ---- epilogue: out = h_512 @ W_ho + b_ho (t=511 wrote hbuf[0]) ----
    if (tid < BT * O_DIM) {
        const int b = tid / O_DIM;
        const int o = tid - b * O_DIM;
        float sum = b_ho[o];
        const char* hb = (const char*)hbuf[0];
        for (int j = 0; j < H_DIM; ++j) {
            int off = (b * 256 + j * 2) ^ (b << 4);
            sum += bf2f(*(const unsigned short*)(hb + off)) * W_ho[j * O_DIM + o];
        }
        out[(size_t)(r0 + b) * O_DIM + o] = sum;
    }
}

extern "C" void kernel_launch(void* const* d_in, const int* in_sizes, int n_in,
                              void* d_out, int out_size, void* d_ws, size_t ws_size,
                              hipStream_t stream) {
    const float* x    = (const float*)d_in[0];
    const float* W_ih = (const float*)d_in[1];
    const float* b_ih = (const float*)d_in[2];
    const float* W_hh = (const float*)d_in[3];
    const float* b_hh = (const float*)d_in[4];
    const float* W_ho = (const float*)d_in[5];
    const float* b_ho = (const float*)d_in[6];
    const int B = in_sizes[0] / (S_LEN * I_DIM);   // 4096
    rnn_fused<<<B / BT, 512, 0, stream>>>(x, W_ih, b_ih, W_hh, b_hh, W_ho, b_ho,
                                          (float*)d_out);
}

// Round 3
// 204.182 us; speedup vs baseline: 1.3003x; 1.3003x over previous
//
#include <hip/hip_runtime.h>
#include <stdint.h>

#define S_LEN 512
#define I_DIM 28
#define H_DIM 128
#define O_DIM 28
#define BT    16   // batch rows per block

typedef __attribute__((ext_vector_type(8))) short bf16x8;
typedef __attribute__((ext_vector_type(4))) float f32x4;

__device__ __forceinline__ short f2bf(float f) {        // cold paths only
    unsigned u = __float_as_uint(f);
    u = (u + 0x7fffu + ((u >> 16) & 1u)) >> 16;
    return (short)u;
}
__device__ __forceinline__ float bf2f(unsigned short u) {
    return __uint_as_float(((unsigned)u) << 16);
}
__device__ __forceinline__ unsigned cvt_pk(float a, float b) {
    unsigned r;
    asm("v_cvt_pk_bf16_f32 %0, %1, %2" : "=v"(r) : "v"(a), "v"(b));
    return r;
}
// tanh(a) = 1 - 2/(1+e^{2a}) : 2 trans + 3 VALU
#define TWO_LOG2E 2.8853900817779268f
__device__ __forceinline__ float fast_tanh(float a) {
    float e = __builtin_amdgcn_exp2f(a * TWO_LOG2E);
    float r = __builtin_amdgcn_rcpf(1.0f + e);
    return fmaf(-2.0f, r, 1.0f);
}

__global__ __launch_bounds__(256, 1) void rnn_fused(
    const float* __restrict__ x,
    const float* __restrict__ W_ih, const float* __restrict__ b_ih,
    const float* __restrict__ W_hh, const float* __restrict__ b_hh,
    const float* __restrict__ W_ho, const float* __restrict__ b_ho,
    float* __restrict__ out)
{
    const int tid  = threadIdx.x;
    const int wave = tid >> 6;         // 0..3 -> cols [32w, 32w+32)
    const int lane = tid & 63;
    const int l15  = lane & 15;
    const int lk   = lane >> 4;        // 0..3
    const int r0   = blockIdx.x * BT;
    const int j0   = wave * 32;

    __shared__ __align__(16) unsigned short hbuf[2][BT * H_DIM]; // 8KB, XOR-swizzled
    __shared__ bf16x8 xring[8][64];                              // x A-frag ring, 8KB

    // ---- constant B fragments: 2 j-tiles x 4 k-chunks of W_hh, 2 of W_ih ----
    bf16x8 bw[2][4];
    bf16x8 bx[2];
    float bias[2];
    #pragma unroll
    for (int ti = 0; ti < 2; ++ti) {
        const int col = j0 + ti * 16 + l15;
        #pragma unroll
        for (int kk = 0; kk < 4; ++kk)
            #pragma unroll
            for (int e = 0; e < 8; ++e)
                bw[ti][kk][e] = f2bf(W_hh[(kk * 32 + lk * 8 + e) * H_DIM + col]);
        #pragma unroll
        for (int e = 0; e < 8; ++e) {
            int k = lk * 8 + e;
            bx[ti][e] = (k < I_DIM) ? f2bf(W_ih[k * H_DIM + col]) : (short)0;
        }
        bias[ti] = b_ih[col] + b_hh[col];
    }

    // ---- LDS byte offsets ----
    int ha_off[4];                     // A-frag reads: row=l15, k=kk*32+lk*8
    #pragma unroll
    for (int kk = 0; kk < 4; ++kk)
        ha_off[kk] = ((l15 * 256) + (kk * 64) + (lk * 16)) ^ ((l15 & 7) << 4);
    int hw_off[2][4];                  // C writes: row=lk*4+r, col=j0+ti*16+l15
    #pragma unroll
    for (int ti = 0; ti < 2; ++ti)
        #pragma unroll
        for (int r = 0; r < 4; ++r) {
            int row = lk * 4 + r;
            hw_off[ti][r] = (row * 256 + (j0 + ti * 16 + l15) * 2) ^ ((row & 7) << 4);
        }

    for (int i = tid; i < BT * H_DIM; i += 256) hbuf[0][i] = 0;  // h0 = 0

    const bool hasHi = (lk < 3);       // k-group 3: only k=24..27 valid
    const float* xbase = x + (size_t)(r0 + l15) * S_LEN * I_DIM + lk * 8;

    // ---- prologue: wave w stages frame w (frames 0..3) ----
    {
        const float* src = xbase + wave * I_DIM;
        float4 lo = *(const float4*)src;
        float4 hi = hasHi ? *(const float4*)(src + 4) : make_float4(0.f,0.f,0.f,0.f);
        union { bf16x8 v; unsigned u[4]; } f;
        f.u[0] = cvt_pk(lo.x, lo.y); f.u[1] = cvt_pk(lo.z, lo.w);
        f.u[2] = cvt_pk(hi.x, hi.y); f.u[3] = cvt_pk(hi.z, hi.w);
        xring[wave][lane] = f.v;
    }
    asm volatile("s_waitcnt lgkmcnt(0)" ::: "memory");
    __builtin_amdgcn_s_barrier();
    asm volatile("" ::: "memory");

    // ---- time loop: 4 steps per group ----
    for (int t4 = 0; t4 < S_LEN; t4 += 4) {
        const int tf = t4 + 4 + wave;                  // frame this wave prefetches
        float4 pf_lo = make_float4(0.f,0.f,0.f,0.f), pf_hi = pf_lo;
        if (tf < S_LEN) {
            const float* src = xbase + (size_t)tf * I_DIM;
            pf_lo = *(const float4*)src;
            if (hasHi) pf_hi = *(const float4*)(src + 4);
        }
        bf16x8 axf[4];
        #pragma unroll
        for (int p = 0; p < 4; ++p)
            axf[p] = xring[(t4 + p) & 7][lane];

        #pragma unroll
        for (int p = 0; p < 4; ++p) {
            const char* rb = (const char*)hbuf[p & 1];
            char*       wb = (char*)hbuf[(p & 1) ^ 1];

            // issue h A-frag reads first (latency), x-MFMAs fill the gap
            bf16x8 ah0 = *(const bf16x8*)(rb + ha_off[0]);
            bf16x8 ah1 = *(const bf16x8*)(rb + ha_off[1]);
            bf16x8 ah2 = *(const bf16x8*)(rb + ha_off[2]);
            bf16x8 ah3 = *(const bf16x8*)(rb + ha_off[3]);

            f32x4 a0 = {bias[0], bias[0], bias[0], bias[0]};
            f32x4 a1 = {bias[1], bias[1], bias[1], bias[1]};
            a0 = __builtin_amdgcn_mfma_f32_16x16x32_bf16(axf[p], bx[0], a0, 0, 0, 0);
            a1 = __builtin_amdgcn_mfma_f32_16x16x32_bf16(axf[p], bx[1], a1, 0, 0, 0);
            a0 = __builtin_amdgcn_mfma_f32_16x16x32_bf16(ah0, bw[0][0], a0, 0, 0, 0);
            a1 = __builtin_amdgcn_mfma_f32_16x16x32_bf16(ah0, bw[1][0], a1, 0, 0, 0);
            a0 = __builtin_amdgcn_mfma_f32_16x16x32_bf16(ah1, bw[0][1], a0, 0, 0, 0);
            a1 = __builtin_amdgcn_mfma_f32_16x16x32_bf16(ah1, bw[1][1], a1, 0, 0, 0);
            a0 = __builtin_amdgcn_mfma_f32_16x16x32_bf16(ah2, bw[0][2], a0, 0, 0, 0);
            a1 = __builtin_amdgcn_mfma_f32_16x16x32_bf16(ah2, bw[1][2], a1, 0, 0, 0);
            a0 = __builtin_amdgcn_mfma_f32_16x16x32_bf16(ah3, bw[0][3], a0, 0, 0, 0);
            a1 = __builtin_amdgcn_mfma_f32_16x16x32_bf16(ah3, bw[1][3], a1, 0, 0, 0);

            #pragma unroll
            for (int r = 0; r < 4; ++r) {
                float h0v = fast_tanh(a0[r]);
                float h1v = fast_tanh(a1[r]);
                *(unsigned short*)(wb + hw_off[0][r]) = (unsigned short)cvt_pk(h0v, h0v);
                *(unsigned short*)(wb + hw_off[1][r]) = (unsigned short)cvt_pk(h1v, h1v);
            }
            if (p == 2 && tf < S_LEN) {               // late ring write of prefetch
                union { bf16x8 v; unsigned u[4]; } f;
                f.u[0] = cvt_pk(pf_lo.x, pf_lo.y); f.u[1] = cvt_pk(pf_lo.z, pf_lo.w);
                f.u[2] = cvt_pk(pf_hi.x, pf_hi.y); f.u[3] = cvt_pk(pf_hi.z, pf_hi.w);
                xring[tf & 7][lane] = f.v;
            }
            asm volatile("s_waitcnt lgkmcnt(0)" ::: "memory");
            __builtin_amdgcn_s_barrier();
            asm volatile("" ::: "memory");
        }
    }

    // ---- epilogue: out = h_512 @ W_ho + b_ho (t=511 wrote hbuf[0]) ----
    for (int idx = tid; idx < BT * O_DIM; idx += 256) {
        const int b = idx / O_DIM;
        const int o = idx - b * O_DIM;
        float sum = b_ho[o];
        const char* hb = (const char*)hbuf[0];
        for (int j = 0; j < H_DIM; ++j) {
            int off = (b * 256 + j * 2) ^ ((b & 7) << 4);
            sum += bf2f(*(const unsigned short*)(hb + off)) * W_ho[j * O_DIM + o];
        }
        out[(size_t)(r0 + b) * O_DIM + o] = sum;
    }
}

extern "C" void kernel_launch(void* const* d_in, const int* in_sizes, int n_in,
                              void* d_out, int out_size, void* d_ws, size_t ws_size,
                              hipStream_t stream) {
    const float* x    = (const float*)d_in[0];
    const float* W_ih = (const float*)d_in[1];
    const float* b_ih = (const float*)d_in[2];
    const float* W_hh = (const float*)d_in[3];
    const float* b_hh = (const float*)d_in[4];
    const float* W_ho = (const float*)d_in[5];
    const float* b_ho = (const float*)d_in[6];
    const int B = in_sizes[0] / (S_LEN * I_DIM);   // 4096
    rnn_fused<<<B / BT, 256, 0, stream>>>(x, W_ih, b_ih, W_hh, b_hh, W_ho, b_ho,
                                          (float*)d_out);
}